// Round 1
// baseline (64.967 us; speedup 1.0000x reference)
//
#include <hip/hip_runtime.h>

#define NEG_INF (-1e30f)

static constexpr int Bn = 64;
static constexpr int Sn = 512;
static constexpr int Hn = 768;
static constexpr int Tn = 9;
static constexpr int KC = 32;   // number of chunks over steps 1..511
static constexpr int CL = 16;   // chunk length

__device__ __forceinline__ float dot4(float4 a, float4 b) {
    return a.x * b.x + a.y * b.y + a.z * b.z + a.w * b.w;
}

// K1: emissions[b,s,t] = relu(dot(emb[b,s,:], W[t,:]) + bias[t])
// One wave per row, W held in registers (108 VGPRs), grid-stride over rows.
__global__ __launch_bounds__(256) void emis_kernel(const float* __restrict__ emb,
        const float* __restrict__ Wm, const float* __restrict__ bias,
        float* __restrict__ em) {
    const int lane = threadIdx.x & 63;
    const int gwave = (blockIdx.x * 256 + threadIdx.x) >> 6;
    const int nwaves = gridDim.x * 4;

    float4 w[Tn][3];
#pragma unroll
    for (int t = 0; t < Tn; ++t) {
        const float4* w4 = (const float4*)(Wm + t * Hn);
#pragma unroll
        for (int i = 0; i < 3; ++i) w[t][i] = w4[lane + (i << 6)];
    }
    float bb[Tn];
#pragma unroll
    for (int t = 0; t < Tn; ++t) bb[t] = bias[t];

    for (int row = gwave; row < Bn * Sn; row += nwaves) {
        const float4* e4 = (const float4*)(emb + (size_t)row * Hn);
        float4 e0 = e4[lane];
        float4 e1 = e4[lane + 64];
        float4 e2 = e4[lane + 128];
        float acc[Tn];
#pragma unroll
        for (int t = 0; t < Tn; ++t)
            acc[t] = dot4(e0, w[t][0]) + dot4(e1, w[t][1]) + dot4(e2, w[t][2]);
#pragma unroll
        for (int t = 0; t < Tn; ++t) {
#pragma unroll
            for (int off = 32; off; off >>= 1)
                acc[t] += __shfl_xor(acc[t], off);
        }
        if (lane == 0) {
#pragma unroll
            for (int t = 0; t < Tn; ++t)
                em[(size_t)row * Tn + t] = fmaxf(acc[t] + bb[t], 0.0f);
        }
    }
}

// K2: per (batch, chunk) compose the 9x9 log-semiring matrices of CL steps.
// A_t[i][j] = trans[i][j] + em[t][j] if mask_bool[t] else Identity (skipped).
// Block = 128 threads; threads 0..80 map to (i,j) of the matrix.
__global__ __launch_bounds__(128) void chunk_kernel(const float* __restrict__ em,
        const float* __restrict__ trans, const int* __restrict__ labels,
        const int* __restrict__ mask, float* __restrict__ chunkM) {
    const int bk = blockIdx.x;
    const int b = bk >> 5;     // / KC
    const int k = bk & 31;     // % KC
    const int tid = threadIdx.x;
    const int i = tid / 9;
    const int j = tid - i * 9;
    const int t0 = 1 + k * CL;

    __shared__ float P[2][81];
    __shared__ float em_s[CL * Tn];
    __shared__ int on_s[CL];

    // stage emissions + step-enable flags for this chunk
    {
        const int nst = (Sn - t0 < CL) ? (Sn - t0) : CL;
        const int base = (b * Sn + t0) * Tn;
        for (int u = tid; u < nst * Tn; u += 128) em_s[u] = em[base + u];
        if (tid < CL) {
            int t = t0 + tid;
            int on = 0;
            if (t < Sn)
                on = (mask[b * Sn + t] != 0) && (labels[b * Sn + t] != -100);
            on_s[tid] = on;
        }
    }

    float c[Tn];
    if (tid < 81) {
#pragma unroll
        for (int kk = 0; kk < Tn; ++kk) c[kk] = trans[kk * Tn + j];
        P[0][tid] = (i == j) ? 0.0f : NEG_INF;
    }
    __syncthreads();

    int cur = 0;
#pragma unroll
    for (int u = 0; u < CL; ++u) {
        if (!on_s[u]) continue;   // uniform across block
        if (tid < 81) {
            float x[Tn];
#pragma unroll
            for (int kk = 0; kk < Tn; ++kk) x[kk] = P[cur][i * 9 + kk] + c[kk];
            float mx = x[0];
#pragma unroll
            for (int kk = 1; kk < Tn; ++kk) mx = fmaxf(mx, x[kk]);
            float s = 0.0f;
#pragma unroll
            for (int kk = 0; kk < Tn; ++kk) s += __expf(x[kk] - mx);
            P[cur ^ 1][tid] = mx + __logf(s) + em_s[u * Tn + j];
        }
        __syncthreads();
        cur ^= 1;
    }
    if (tid < 81) chunkM[(size_t)bk * 81 + tid] = P[cur][tid];
}

// K3: per batch (one wave): alpha0 ⊗ P_0 ⊗ ... ⊗ P_{KC-1}, denom, numerator, nll[b]
__global__ __launch_bounds__(64) void combine_kernel(const float* __restrict__ em,
        const float* __restrict__ chunkM, const float* __restrict__ startT,
        const float* __restrict__ trans, const float* __restrict__ endT,
        const int* __restrict__ labels, const int* __restrict__ mask,
        float* __restrict__ nll) {
    const int b = blockIdx.x;
    const int lane = threadIdx.x;

    float alpha = NEG_INF;
    if (lane < Tn) alpha = startT[lane] + em[((size_t)b * Sn) * Tn + lane];

    for (int k = 0; k < KC; ++k) {
        const float* P = chunkM + ((size_t)b * KC + k) * 81;
        float a[Tn];
#pragma unroll
        for (int i = 0; i < Tn; ++i) a[i] = __shfl(alpha, i);
        float na = NEG_INF;
        if (lane < Tn) {
            float x[Tn];
#pragma unroll
            for (int i = 0; i < Tn; ++i) x[i] = a[i] + P[i * Tn + lane];
            float mx = x[0];
#pragma unroll
            for (int i = 1; i < Tn; ++i) mx = fmaxf(mx, x[i]);
            float s = 0.0f;
#pragma unroll
            for (int i = 0; i < Tn; ++i) s += __expf(x[i] - mx);
            na = mx + __logf(s);
        }
        alpha = na;
    }

    // denom = logsumexp(alpha + end_trans)
    float z = (lane < Tn) ? (alpha + endT[lane]) : NEG_INF;
    float mx = z;
#pragma unroll
    for (int off = 32; off; off >>= 1) mx = fmaxf(mx, __shfl_xor(mx, off));
    float s = __expf(z - mx);   // lanes >= Tn underflow to 0
#pragma unroll
    for (int off = 32; off; off >>= 1) s += __shfl_xor(s, off);
    float denom = mx + __logf(s);

    // numerator pieces
    float nump = 0.0f;
    int cnt = 0;
    for (int t = lane; t < Sn; t += 64) {
        int m = mask[b * Sn + t];
        int lab = labels[b * Sn + t];
        bool valid = (lab != -100);
        bool mb = (m != 0) && valid;
        cnt += mb ? 1 : 0;
        if (t >= 1 && mb) {
            int labm = valid ? lab : 0;
            int labp = labels[b * Sn + t - 1];
            labp = (labp != -100) ? labp : 0;
            nump += em[((size_t)b * Sn + t) * Tn + labm] + trans[labp * Tn + labm];
        }
    }
#pragma unroll
    for (int off = 32; off; off >>= 1) {
        nump += __shfl_xor(nump, off);
        cnt += __shfl_xor(cnt, off);
    }

    if (lane == 0) {
        int lab0 = labels[b * Sn];
        lab0 = (lab0 != -100) ? lab0 : 0;
        float first = startT[lab0] + em[((size_t)b * Sn) * Tn + lab0];
        int lastIdx = cnt - 1;
        if (lastIdx < 0) lastIdx = 0;
        int lastLab = labels[b * Sn + lastIdx];
        lastLab = (lastLab != -100) ? lastLab : 0;
        float num = first + nump + endT[lastLab];
        nll[b] = denom - num;
    }
}

// K4: mean over 64 per-batch nll values (deterministic, no atomics)
__global__ __launch_bounds__(64) void mean_kernel(const float* __restrict__ nll,
        float* __restrict__ out) {
    float v = nll[threadIdx.x];
#pragma unroll
    for (int off = 32; off; off >>= 1) v += __shfl_xor(v, off);
    if (threadIdx.x == 0) out[0] = v * (1.0f / 64.0f);
}

extern "C" void kernel_launch(void* const* d_in, const int* in_sizes, int n_in,
                              void* d_out, int out_size, void* d_ws, size_t ws_size,
                              hipStream_t stream) {
    const float* emb    = (const float*)d_in[0];
    const float* Wm     = (const float*)d_in[1];
    const float* bias   = (const float*)d_in[2];
    const float* startT = (const float*)d_in[3];
    const float* trans  = (const float*)d_in[4];
    const float* endT   = (const float*)d_in[5];
    const int*   labels = (const int*)d_in[6];
    const int*   mask   = (const int*)d_in[7];

    float* em     = (float*)d_ws;                       // B*S*T floats
    float* chunkM = em + (size_t)Bn * Sn * Tn;          // B*KC*81 floats
    float* nll    = chunkM + (size_t)Bn * KC * 81;      // B floats
    float* out    = (float*)d_out;

    emis_kernel<<<768, 256, 0, stream>>>(emb, Wm, bias, em);
    chunk_kernel<<<Bn * KC, 128, 0, stream>>>(em, trans, labels, mask, chunkM);
    combine_kernel<<<Bn, 64, 0, stream>>>(em, chunkM, startT, trans, endT, labels, mask, nll);
    mean_kernel<<<1, 64, 0, stream>>>(nll, out);
}

// Round 2
// 61.046 us; speedup vs baseline: 1.0642x; 1.0642x over previous
//
#include <hip/hip_runtime.h>

#define NEG_INF (-1e30f)

static constexpr int Bn = 64;
static constexpr int Sn = 512;
static constexpr int Hn = 768;
static constexpr int Tn = 9;
static constexpr int KC = 32;      // chunks over steps 1..511
static constexpr int CL = 16;      // chunk length
static constexpr int PSTRIDE = 108; // 9 cols * 12 (padded rows, 16B aligned)

__device__ __forceinline__ float dot4(float4 a, float4 b) {
    return a.x * b.x + a.y * b.y + a.z * b.z + a.w * b.w;
}

// Fused: emissions for this chunk's 16 rows (relu(emb@W^T+b)) -> LDS,
// then 9x9 log-semiring chunk matrix + partial numerator/count.
// Block = 128 threads (2 waves). Grid = B*KC = 2048.
__global__ __launch_bounds__(128) void fused_chunk_kernel(
        const float* __restrict__ emb, const float* __restrict__ Wm,
        const float* __restrict__ bias, const float* __restrict__ trans,
        const int* __restrict__ labels, const int* __restrict__ mask,
        float* __restrict__ chunkP, float* __restrict__ auxN,
        int* __restrict__ auxC) {
    const int bk = blockIdx.x;
    const int b  = bk >> 5;
    const int k  = bk & 31;
    const int t0 = 1 + k * CL;
    const int tid  = threadIdx.x;
    const int w    = tid >> 6;
    const int lane = tid & 63;

    __shared__ float em_s[CL][Tn];
    __shared__ int   on_s[CL];
    __shared__ float tr_s[81];

    // W fragment in registers: lane covers h = lane*4 + {0..3} + 256*i
    float4 wr[Tn][3];
#pragma unroll
    for (int t = 0; t < Tn; ++t) {
        const float4* w4 = (const float4*)(Wm + t * Hn);
#pragma unroll
        for (int i = 0; i < 3; ++i) wr[t][i] = w4[lane + (i << 6)];
    }
    float bb[Tn];
#pragma unroll
    for (int t = 0; t < Tn; ++t) bb[t] = bias[t];

    if (tid < 81) tr_s[tid] = trans[tid];

    // labels / mask / step-enable for this chunk (lanes 0..15 of wave 0)
    int myLab = 0, myLabP = 0, myOn = 0;
    if (tid < CL) {
        int t = t0 + tid;
        if (t < Sn) {
            int lb = labels[b * Sn + t];
            int lp = labels[b * Sn + t - 1];
            int mm = mask[b * Sn + t];
            myOn  = (mm != 0) && (lb != -100);
            myLab = (lb == -100) ? 0 : lb;
            myLabP = (lp == -100) ? 0 : lp;
        }
        on_s[tid] = myOn;
    }

    // ---- emissions: wave w computes rows w*8 .. w*8+7 (one wave-row at a time)
#pragma unroll
    for (int rr = 0; rr < 8; ++rr) {
        const int r = w * 8 + rr;
        const int t = t0 + r;
        const int trow = (t < Sn) ? t : (Sn - 1);  // clamp; unused if OOB
        const float4* e4 = (const float4*)(emb + ((size_t)b * Sn + trow) * Hn);
        float4 e0 = e4[lane];
        float4 e1 = e4[lane + 64];
        float4 e2 = e4[lane + 128];
        float acc[Tn];
#pragma unroll
        for (int t9 = 0; t9 < Tn; ++t9)
            acc[t9] = dot4(e0, wr[t9][0]) + dot4(e1, wr[t9][1]) + dot4(e2, wr[t9][2]);
#pragma unroll
        for (int t9 = 0; t9 < Tn; ++t9) {
#pragma unroll
            for (int off = 32; off; off >>= 1)
                acc[t9] += __shfl_xor(acc[t9], off);
        }
        if (lane == 0) {
#pragma unroll
            for (int t9 = 0; t9 < Tn; ++t9)
                em_s[r][t9] = fmaxf(acc[t9] + bb[t9], 0.0f);
        }
    }
    __syncthreads();

    // ---- partial numerator + mask count for this chunk (wave 0, lanes 0..15)
    float nump = 0.0f;
    int cnt = 0;
    if (tid < CL && myOn) {
        nump = em_s[tid][myLab] + tr_s[myLabP * Tn + myLab];
        cnt = 1;
    }
    if (w == 0) {
#pragma unroll
        for (int off = 8; off; off >>= 1) {
            nump += __shfl_xor(nump, off);
            cnt  += __shfl_xor(cnt, off);
        }
        if (lane == 0) { auxN[bk] = nump; auxC[bk] = cnt; }
    }

    // ---- chunk matrix: 9 basis row-vectors propagated in-register.
    // wave 0: rows 0..4 (lanes 0..44); wave 1: rows 5..8 (lanes 0..35)
    const int v  = lane / 9;
    const int jj = lane - v * 9;
    const bool act = lane < ((w == 0) ? 45 : 36);
    const int rid = (w == 0) ? v : (5 + v);

    float c[Tn];
#pragma unroll
    for (int kk = 0; kk < Tn; ++kk) c[kk] = tr_s[kk * Tn + jj];

    float pv = (act && rid == jj) ? 0.0f : NEG_INF;

    for (int u = 0; u < CL; ++u) {
        if (!on_s[u]) continue;   // block-uniform
        float x[Tn];
#pragma unroll
        for (int kk = 0; kk < Tn; ++kk) {
            float a = __shfl(pv, (v * Tn + kk) & 63);
            x[kk] = a + c[kk];
        }
        float mx = x[0];
#pragma unroll
        for (int kk = 1; kk < Tn; ++kk) mx = fmaxf(mx, x[kk]);
        float s = 0.0f;
#pragma unroll
        for (int kk = 0; kk < Tn; ++kk) s += __expf(x[kk] - mx);
        float nv = mx + __logf(s) + em_s[u][jj];
        pv = act ? nv : pv;
    }
    if (act) chunkP[(size_t)bk * PSTRIDE + jj * 12 + rid] = pv;
}

// Combine per batch: one wave. alpha0 from in-kernel em row 0, then 32
// prefetched chunk-matrix applications, denom, numerator assembly, nll[b].
__global__ __launch_bounds__(64) void combine_kernel(
        const float* __restrict__ emb, const float* __restrict__ Wm,
        const float* __restrict__ bias, const float* __restrict__ startT,
        const float* __restrict__ endT, const int* __restrict__ labels,
        const int* __restrict__ mask, const float* __restrict__ chunkP,
        const float* __restrict__ auxN, const int* __restrict__ auxC,
        float* __restrict__ nll) {
    const int b = blockIdx.x;
    const int lane = threadIdx.x;

    // emissions for row (b, 0)
    float4 wr[Tn][3];
#pragma unroll
    for (int t = 0; t < Tn; ++t) {
        const float4* w4 = (const float4*)(Wm + t * Hn);
#pragma unroll
        for (int i = 0; i < 3; ++i) wr[t][i] = w4[lane + (i << 6)];
    }
    const float4* e4 = (const float4*)(emb + (size_t)b * Sn * Hn);
    float4 e0 = e4[lane];
    float4 e1 = e4[lane + 64];
    float4 e2 = e4[lane + 128];
    float acc[Tn];
#pragma unroll
    for (int t = 0; t < Tn; ++t)
        acc[t] = dot4(e0, wr[t][0]) + dot4(e1, wr[t][1]) + dot4(e2, wr[t][2]);
#pragma unroll
    for (int t = 0; t < Tn; ++t) {
#pragma unroll
        for (int off = 32; off; off >>= 1)
            acc[t] += __shfl_xor(acc[t], off);
    }
    float em0 = NEG_INF;   // lane t < 9 holds em[b,0,t]
#pragma unroll
    for (int t = 0; t < Tn; ++t) {
        float vt = fmaxf(acc[t] + bias[t], 0.0f);
        if (lane == t) em0 = vt;
    }
    float alpha = (lane < Tn) ? (startT[lane] + em0) : NEG_INF;

    int lab0r = labels[b * Sn];
    int lab0 = (lab0r == -100) ? 0 : lab0r;
    float first = startT[lab0] + __shfl(em0, lab0);

    // aux partial sums (lanes 0..31), full butterfly (lanes>=32 contribute 0)
    float numP = (lane < KC) ? auxN[b * KC + lane] : 0.0f;
    int   cntP = (lane < KC) ? auxC[b * KC + lane] : 0;
#pragma unroll
    for (int off = 32; off; off >>= 1) {
        numP += __shfl_xor(numP, off);
        cntP += __shfl_xor(cntP, off);
    }
    int m0 = ((mask[b * Sn] != 0) && (lab0r != -100)) ? 1 : 0;
    int cntTot = cntP + m0;
    int lastIdx = cntTot - 1;
    if (lastIdx < 0) lastIdx = 0;
    int lastLab = labels[b * Sn + lastIdx];
    lastLab = (lastLab == -100) ? 0 : lastLab;
    float num = first + numP + endT[lastLab];

    // 32 chunk applications with software prefetch
    const float* Pb = chunkP + (size_t)b * KC * PSTRIDE;
    float4 p0 = make_float4(0, 0, 0, 0), p1 = p0, p2 = p0;
    if (lane < Tn) {
        const float4* pp = (const float4*)(Pb + lane * 12);
        p0 = pp[0]; p1 = pp[1]; p2 = pp[2];
    }
    for (int k = 0; k < KC; ++k) {
        float4 q0 = p0, q1 = p1, q2 = p2;
        if (k + 1 < KC && lane < Tn) {
            const float4* pp = (const float4*)(Pb + (size_t)(k + 1) * PSTRIDE + lane * 12);
            p0 = pp[0]; p1 = pp[1]; p2 = pp[2];
        }
        float av[Tn];
#pragma unroll
        for (int i = 0; i < Tn; ++i) av[i] = __shfl(alpha, i);
        float x[Tn];
        x[0] = av[0] + q0.x; x[1] = av[1] + q0.y; x[2] = av[2] + q0.z;
        x[3] = av[3] + q0.w; x[4] = av[4] + q1.x; x[5] = av[5] + q1.y;
        x[6] = av[6] + q1.z; x[7] = av[7] + q1.w; x[8] = av[8] + q2.x;
        float mx = x[0];
#pragma unroll
        for (int i = 1; i < Tn; ++i) mx = fmaxf(mx, x[i]);
        float s = 0.0f;
#pragma unroll
        for (int i = 0; i < Tn; ++i) s += __expf(x[i] - mx);
        float na = mx + __logf(s);
        alpha = (lane < Tn) ? na : NEG_INF;
    }

    // denom = logsumexp(alpha + end)
    float z = (lane < Tn) ? (alpha + endT[lane]) : NEG_INF;
    float mx = z;
#pragma unroll
    for (int off = 32; off; off >>= 1) mx = fmaxf(mx, __shfl_xor(mx, off));
    float s = __expf(z - mx);
#pragma unroll
    for (int off = 32; off; off >>= 1) s += __shfl_xor(s, off);
    float denom = mx + __logf(s);

    if (lane == 0) nll[b] = denom - num;
}

__global__ __launch_bounds__(64) void mean_kernel(const float* __restrict__ nll,
        float* __restrict__ out) {
    float v = nll[threadIdx.x];
#pragma unroll
    for (int off = 32; off; off >>= 1) v += __shfl_xor(v, off);
    if (threadIdx.x == 0) out[0] = v * (1.0f / 64.0f);
}

extern "C" void kernel_launch(void* const* d_in, const int* in_sizes, int n_in,
                              void* d_out, int out_size, void* d_ws, size_t ws_size,
                              hipStream_t stream) {
    const float* emb    = (const float*)d_in[0];
    const float* Wm     = (const float*)d_in[1];
    const float* bias   = (const float*)d_in[2];
    const float* startT = (const float*)d_in[3];
    const float* trans  = (const float*)d_in[4];
    const float* endT   = (const float*)d_in[5];
    const int*   labels = (const int*)d_in[6];
    const int*   mask   = (const int*)d_in[7];

    float* chunkP = (float*)d_ws;                        // B*KC*108 floats
    float* auxN   = chunkP + (size_t)Bn * KC * PSTRIDE;  // B*KC floats
    int*   auxC   = (int*)(auxN + (size_t)Bn * KC);      // B*KC ints
    float* nll    = (float*)(auxC + (size_t)Bn * KC);    // B floats
    float* out    = (float*)d_out;

    fused_chunk_kernel<<<Bn * KC, 128, 0, stream>>>(emb, Wm, bias, trans,
                                                    labels, mask, chunkP, auxN, auxC);
    combine_kernel<<<Bn, 64, 0, stream>>>(emb, Wm, bias, startT, endT,
                                          labels, mask, chunkP, auxN, auxC, nll);
    mean_kernel<<<1, 64, 0, stream>>>(nll, out);
}